// Round 4
// baseline (517.608 us; speedup 1.0000x reference)
//
#include <hip/hip_runtime.h>
#include <stdint.h>

// N=M=16384, D=64 fp32. dist[n,m] = a_sq[n] + b_sq[m] - 2 a.b; out = sum_n min_m.
// Orientation: A(streamed) = TO points (K=80: dims 0..63, bsq at k=64),
// B(resident) = -2*FROM (K=64 + constant 1.0 ext fragment). C[row=to][col=from]
// -> per-lane min3-tree over 16 rows => 1 running min per col-subtile.
#define N_PTS 16384
#define KDIM_A 80
#define KDIM_B 64
#define NBLOCKS 1024          // 4 blocks/CU x 256 CUs: exactly co-resident
#define TSPLITS 16
#define TO_CHUNK (N_PTS / TSPLITS)   // 1024 TO pts per wave
#define TO_TILES (TO_CHUNK / 32)     // 32 tiles of 32 TO pts

typedef __attribute__((ext_vector_type(8)))  short bf16x8;
typedef __attribute__((ext_vector_type(16))) float f32x16;

__device__ __forceinline__ unsigned flipf(float f) {
    unsigned u = __float_as_uint(f);
    return u ^ (unsigned)((((int)u) >> 31) | (int)0x80000000);
}
__device__ __forceinline__ float unflipf(unsigned k) {
    unsigned u = (k & 0x80000000u) ? (k ^ 0x80000000u) : ~k;
    return __uint_as_float(u);
}
__device__ __forceinline__ unsigned short f2bf(float f) {
    unsigned u = __float_as_uint(f);
    u += 0x7FFFu + ((u >> 16) & 1u);   // RNE
    return (unsigned short)(u >> 16);
}
__device__ __forceinline__ float tree16(f32x16 a) {
    float m0 = fminf(fminf(a[0],  a[1]),  a[2]);
    float m1 = fminf(fminf(a[3],  a[4]),  a[5]);
    float m2 = fminf(fminf(a[6],  a[7]),  a[8]);
    float m3 = fminf(fminf(a[9],  a[10]), a[11]);
    float m4 = fminf(fminf(a[12], a[13]), a[14]);
    float m5 = fminf(fminf(a[15], m0), m1);
    return fminf(fminf(fminf(m2, m3), m4), m5);
}

// Grid-wide barrier: all NBLOCKS are co-resident (exact-capacity grid +
// launch_bounds), counters pre-zeroed by a captured hipMemsetAsync.
// Agent scope => L2 writeback/invalidate across XCDs.
__device__ __forceinline__ void grid_barrier(unsigned* cnt, unsigned target) {
    __syncthreads();
    if (threadIdx.x == 0) {
        __hip_atomic_fetch_add(cnt, 1u, __ATOMIC_ACQ_REL, __HIP_MEMORY_SCOPE_AGENT);
        while (__hip_atomic_load(cnt, __ATOMIC_ACQUIRE, __HIP_MEMORY_SCOPE_AGENT) < target)
            __builtin_amdgcn_s_sleep(2);
    }
    __syncthreads();
}

#define CHAIN(X, BF, RM)                                                        \
    {                                                                           \
        f32x16 acc = __builtin_amdgcn_mfma_f32_32x32x16_bf16(X[0], BF[0], zero, 0, 0, 0); \
        acc = __builtin_amdgcn_mfma_f32_32x32x16_bf16(X[1], BF[1], acc, 0, 0, 0); \
        acc = __builtin_amdgcn_mfma_f32_32x32x16_bf16(X[2], BF[2], acc, 0, 0, 0); \
        acc = __builtin_amdgcn_mfma_f32_32x32x16_bf16(X[3], BF[3], acc, 0, 0, 0); \
        acc = __builtin_amdgcn_mfma_f32_32x32x16_bf16(X[4], Bext, acc, 0, 0, 0); \
        RM = fminf(RM, tree16(acc));                                            \
    }

__global__ __launch_bounds__(256, 4) void fused_kernel(
        const float* __restrict__ from_pts, const float* __restrict__ to_pts,
        unsigned short* __restrict__ Bfrom, unsigned short* __restrict__ Ato,
        float* __restrict__ a_sq, unsigned* __restrict__ minkeys,
        unsigned* __restrict__ bar, float* __restrict__ out) {
    const int tid = threadIdx.x;
    const int gid = blockIdx.x * 256 + tid;

    // ---------- phase 0: convert to bf16 operands, norms, init ----------
    {
        int row = gid >> 3;                 // 0..32767 (FROM then TO)
        int sub = gid & 7;                  // 8 threads per row
        bool isFrom = row < N_PTS;
        int r = row & (N_PTS - 1);
        const float* src = isFrom ? from_pts : to_pts;
        float4 v0 = ((const float4*)src)[r * 16 + sub * 2];
        float4 v1 = ((const float4*)src)[r * 16 + sub * 2 + 1];
        float s = v0.x*v0.x + v0.y*v0.y + v0.z*v0.z + v0.w*v0.w
                + v1.x*v1.x + v1.y*v1.y + v1.z*v1.z + v1.w*v1.w;
        s += __shfl_xor(s, 1); s += __shfl_xor(s, 2); s += __shfl_xor(s, 4);
        float sc = isFrom ? -2.0f : 1.0f;
        union { unsigned short u[8]; uint4 q; } w;
        w.u[0] = f2bf(v0.x * sc); w.u[1] = f2bf(v0.y * sc);
        w.u[2] = f2bf(v0.z * sc); w.u[3] = f2bf(v0.w * sc);
        w.u[4] = f2bf(v1.x * sc); w.u[5] = f2bf(v1.y * sc);
        w.u[6] = f2bf(v1.z * sc); w.u[7] = f2bf(v1.w * sc);
        if (isFrom) {
            *(uint4*)(Bfrom + (size_t)r * KDIM_B + sub * 8) = w.q;
            if (sub == 0) a_sq[r] = s;
        } else {
            *(uint4*)(Ato + (size_t)r * KDIM_A + sub * 8) = w.q;
            if (sub == 0) {                 // ext block: bsq at k=64, zeros after
                uint4 z = {0u, 0u, 0u, 0u};
                uint4 e = z;
                e.x = (unsigned)f2bf(s);
                *(uint4*)(Ato + (size_t)r * KDIM_A + 64) = e;
                *(uint4*)(Ato + (size_t)r * KDIM_A + 72) = z;
            }
        }
        if (gid < N_PTS) minkeys[gid] = 0xFFFFFFFFu;
        if (gid == 0) out[0] = 0.0f;
    }

    grid_barrier(&bar[0], NBLOCKS);

    // ---------- phase 1: MFMA + in-lane min ----------
    {
        const int lane = tid & 63;
        const int l31 = lane & 31;
        const int h   = lane >> 5;
        const int wid = (blockIdx.x << 2) + (tid >> 6);   // 0..4095
        const int fg  = wid & 255;          // 64 FROM pts per wave
        const int ts  = wid >> 8;           // block's 4 waves: same ts (shared A stream)

        // resident FROM fragments, 2 col-subtiles x 4 k-blocks
        bf16x8 Bf0[4], Bf1[4];
        {
            const unsigned short* br = Bfrom + (size_t)(fg * 64 + l31) * KDIM_B + h * 8;
            #pragma unroll
            for (int kb = 0; kb < 4; kb++) {
                Bf0[kb] = *(const bf16x8*)(br + kb * 16);
                Bf1[kb] = *(const bf16x8*)(br + 32 * KDIM_B + kb * 16);
            }
        }
        // constant B ext fragment: B[n][k=64] = 1.0 (h==0, j==0 slot)
        bf16x8 Bext;
        #pragma unroll
        for (int j = 0; j < 8; j++) Bext[j] = 0;
        if (h == 0) Bext[0] = (short)0x3F80;

        f32x16 zero;
        #pragma unroll
        for (int r = 0; r < 16; r++) zero[r] = 0.0f;

        float rmin0 = 3.0e38f, rmin1 = 3.0e38f;
        const unsigned short* ab = Ato + (size_t)(ts * TO_CHUNK + l31) * KDIM_A + h * 8;

        bf16x8 Ac[5], An[5];
        #pragma unroll
        for (int kb = 0; kb < 5; kb++) Ac[kb] = *(const bf16x8*)(ab + kb * 16);

        #pragma unroll 1
        for (int t = 0; t < TO_TILES; t += 2) {
            const unsigned short* a1 = ab + (size_t)(t + 1) * 32 * KDIM_A;
            #pragma unroll
            for (int kb = 0; kb < 5; kb++) An[kb] = *(const bf16x8*)(a1 + kb * 16);
            CHAIN(Ac, Bf0, rmin0)
            CHAIN(Ac, Bf1, rmin1)
            const unsigned short* a2 = ab + (size_t)((t + 2) & (TO_TILES - 1)) * 32 * KDIM_A;
            #pragma unroll
            for (int kb = 0; kb < 5; kb++) Ac[kb] = *(const bf16x8*)(a2 + kb * 16);
            CHAIN(An, Bf0, rmin0)
            CHAIN(An, Bf1, rmin1)
        }

        rmin0 = fminf(rmin0, __shfl_xor(rmin0, 32));
        rmin1 = fminf(rmin1, __shfl_xor(rmin1, 32));
        if (lane < 32) {
            atomicMin(minkeys + fg * 64 + l31,      flipf(rmin0));
            atomicMin(minkeys + fg * 64 + 32 + l31, flipf(rmin1));
        }
    }

    grid_barrier(&bar[1], NBLOCKS);

    // ---------- phase 2: sum a_sq + min over rows ----------
    if (gid < N_PTS) {
        float s = a_sq[gid] + unflipf(minkeys[gid]);
        #pragma unroll
        for (int m = 1; m < 64; m <<= 1) s += __shfl_xor(s, m);
        if ((tid & 63) == 0) atomicAdd(out, s);
    }
}

extern "C" void kernel_launch(void* const* d_in, const int* in_sizes, int n_in,
                              void* d_out, int out_size, void* d_ws, size_t ws_size,
                              hipStream_t stream) {
    const float* from_pts = (const float*)d_in[0];
    const float* to_pts   = (const float*)d_in[1];
    char* ws = (char*)d_ws;
    unsigned*       minkeys = (unsigned*)ws;                          //  64 KB
    float*          a_sq    = (float*)(ws + (64 << 10));              //  64 KB
    unsigned*       bar     = (unsigned*)(ws + (128 << 10));          //  256 B
    unsigned short* Bfrom   = (unsigned short*)(ws + (192 << 10));    //   2 MB
    unsigned short* Ato     = (unsigned short*)(ws + (192 << 10) + (2 << 20)); // 2.56 MB

    hipMemsetAsync(bar, 0, 256, stream);   // barrier counters (graph memset node)
    fused_kernel<<<NBLOCKS, 256, 0, stream>>>(from_pts, to_pts, Bfrom, Ato,
                                              a_sq, minkeys, bar, (float*)d_out);
}

// Round 5
// 319.777 us; speedup vs baseline: 1.6187x; 1.6187x over previous
//
#include <hip/hip_runtime.h>
#include <stdint.h>

// N=M=16384, D=64 fp32. dist[n,m] = a_sq[n] + b_sq[m] - 2 a.b; out = sum_n min_m.
// Orientation: A(streamed) = TO points (K=80: dims 0..63, bsq at k=64),
// B(resident) = -2*FROM (K=64 + constant 1.0 ext fragment). C[row=to][col=from]
// -> per-lane min3-tree over 16 rows => 1 running min per col-subtile.
#define N_PTS 16384
#define KDIM_A 80
#define KDIM_B 64
#define NBLOCKS 1024          // 4 blocks/CU x 256 CUs: exactly co-resident
#define TSPLITS 16
#define TO_CHUNK (N_PTS / TSPLITS)   // 1024 TO pts per wave
#define TO_TILES (TO_CHUNK / 32)     // 32 tiles of 32 TO pts

typedef __attribute__((ext_vector_type(8)))  short bf16x8;
typedef __attribute__((ext_vector_type(16))) float f32x16;

__device__ __forceinline__ unsigned flipf(float f) {
    unsigned u = __float_as_uint(f);
    return u ^ (unsigned)((((int)u) >> 31) | (int)0x80000000);
}
__device__ __forceinline__ float unflipf(unsigned k) {
    unsigned u = (k & 0x80000000u) ? (k ^ 0x80000000u) : ~k;
    return __uint_as_float(u);
}
__device__ __forceinline__ unsigned short f2bf(float f) {
    unsigned u = __float_as_uint(f);
    u += 0x7FFFu + ((u >> 16) & 1u);   // RNE
    return (unsigned short)(u >> 16);
}
__device__ __forceinline__ float tree16(f32x16 a) {
    float m0 = fminf(fminf(a[0],  a[1]),  a[2]);
    float m1 = fminf(fminf(a[3],  a[4]),  a[5]);
    float m2 = fminf(fminf(a[6],  a[7]),  a[8]);
    float m3 = fminf(fminf(a[9],  a[10]), a[11]);
    float m4 = fminf(fminf(a[12], a[13]), a[14]);
    float m5 = fminf(fminf(a[15], m0), m1);
    return fminf(fminf(fminf(m2, m3), m4), m5);
}

// Grid-wide barrier, storm-free version.
// R4 lesson: ACQUIRE polling emits buffer_inv (L1+L2 invalidate) PER POLL ->
// 1024 spinners continuously invalidate every XCD L2 (485 us of stall).
// Here: RELEASE arrival (one wbl2, publishes this block's writes), RELAXED
// agent-scope polling (global_load sc1: coherent-point read, NO invalidate),
// then ONE acquire fence on exit.
__device__ __forceinline__ void grid_barrier(unsigned* cnt, unsigned target) {
    __syncthreads();
    if (threadIdx.x == 0) {
        __hip_atomic_fetch_add(cnt, 1u, __ATOMIC_RELEASE, __HIP_MEMORY_SCOPE_AGENT);
        while (__hip_atomic_load(cnt, __ATOMIC_RELAXED, __HIP_MEMORY_SCOPE_AGENT) < target)
            __builtin_amdgcn_s_sleep(16);   // ~1024 cyc between polls
        __builtin_amdgcn_fence(__ATOMIC_ACQUIRE, "agent");  // one invalidate
    }
    __syncthreads();
}

#define CHAIN(X, BF, RM)                                                        \
    {                                                                           \
        f32x16 acc = __builtin_amdgcn_mfma_f32_32x32x16_bf16(X[0], BF[0], zero, 0, 0, 0); \
        acc = __builtin_amdgcn_mfma_f32_32x32x16_bf16(X[1], BF[1], acc, 0, 0, 0); \
        acc = __builtin_amdgcn_mfma_f32_32x32x16_bf16(X[2], BF[2], acc, 0, 0, 0); \
        acc = __builtin_amdgcn_mfma_f32_32x32x16_bf16(X[3], BF[3], acc, 0, 0, 0); \
        acc = __builtin_amdgcn_mfma_f32_32x32x16_bf16(X[4], Bext, acc, 0, 0, 0); \
        RM = fminf(RM, tree16(acc));                                            \
    }

__global__ __launch_bounds__(256, 4) void fused_kernel(
        const float* __restrict__ from_pts, const float* __restrict__ to_pts,
        unsigned short* __restrict__ Bfrom, unsigned short* __restrict__ Ato,
        float* __restrict__ a_sq, unsigned* __restrict__ minkeys,
        unsigned* __restrict__ bar, float* __restrict__ out) {
    const int tid = threadIdx.x;
    const int gid = blockIdx.x * 256 + tid;

    // ---------- phase 0: convert to bf16 operands, norms, init ----------
    {
        int row = gid >> 3;                 // 0..32767 (FROM then TO)
        int sub = gid & 7;                  // 8 threads per row
        bool isFrom = row < N_PTS;
        int r = row & (N_PTS - 1);
        const float* src = isFrom ? from_pts : to_pts;
        float4 v0 = ((const float4*)src)[r * 16 + sub * 2];
        float4 v1 = ((const float4*)src)[r * 16 + sub * 2 + 1];
        float s = v0.x*v0.x + v0.y*v0.y + v0.z*v0.z + v0.w*v0.w
                + v1.x*v1.x + v1.y*v1.y + v1.z*v1.z + v1.w*v1.w;
        s += __shfl_xor(s, 1); s += __shfl_xor(s, 2); s += __shfl_xor(s, 4);
        float sc = isFrom ? -2.0f : 1.0f;
        union { unsigned short u[8]; uint4 q; } w;
        w.u[0] = f2bf(v0.x * sc); w.u[1] = f2bf(v0.y * sc);
        w.u[2] = f2bf(v0.z * sc); w.u[3] = f2bf(v0.w * sc);
        w.u[4] = f2bf(v1.x * sc); w.u[5] = f2bf(v1.y * sc);
        w.u[6] = f2bf(v1.z * sc); w.u[7] = f2bf(v1.w * sc);
        if (isFrom) {
            *(uint4*)(Bfrom + (size_t)r * KDIM_B + sub * 8) = w.q;
            if (sub == 0) a_sq[r] = s;
        } else {
            *(uint4*)(Ato + (size_t)r * KDIM_A + sub * 8) = w.q;
            if (sub == 0) {                 // ext block: bsq at k=64, zeros after
                uint4 z = {0u, 0u, 0u, 0u};
                uint4 e = z;
                e.x = (unsigned)f2bf(s);
                *(uint4*)(Ato + (size_t)r * KDIM_A + 64) = e;
                *(uint4*)(Ato + (size_t)r * KDIM_A + 72) = z;
            }
        }
        if (gid < N_PTS) minkeys[gid] = 0xFFFFFFFFu;
        if (gid == 0) out[0] = 0.0f;
    }

    grid_barrier(&bar[0], NBLOCKS);

    // ---------- phase 1: MFMA + in-lane min ----------
    {
        const int lane = tid & 63;
        const int l31 = lane & 31;
        const int h   = lane >> 5;
        const int wid = (blockIdx.x << 2) + (tid >> 6);   // 0..4095
        const int fg  = wid & 255;          // 64 FROM pts per wave
        const int ts  = wid >> 8;           // block's 4 waves: same ts (shared A stream)

        // resident FROM fragments, 2 col-subtiles x 4 k-blocks
        bf16x8 Bf0[4], Bf1[4];
        {
            const unsigned short* br = Bfrom + (size_t)(fg * 64 + l31) * KDIM_B + h * 8;
            #pragma unroll
            for (int kb = 0; kb < 4; kb++) {
                Bf0[kb] = *(const bf16x8*)(br + kb * 16);
                Bf1[kb] = *(const bf16x8*)(br + 32 * KDIM_B + kb * 16);
            }
        }
        // constant B ext fragment: B[n][k=64] = 1.0 (h==0, j==0 slot)
        bf16x8 Bext;
        #pragma unroll
        for (int j = 0; j < 8; j++) Bext[j] = 0;
        if (h == 0) Bext[0] = (short)0x3F80;

        f32x16 zero;
        #pragma unroll
        for (int r = 0; r < 16; r++) zero[r] = 0.0f;

        float rmin0 = 3.0e38f, rmin1 = 3.0e38f;
        const unsigned short* ab = Ato + (size_t)(ts * TO_CHUNK + l31) * KDIM_A + h * 8;

        bf16x8 Ac[5], An[5];
        #pragma unroll
        for (int kb = 0; kb < 5; kb++) Ac[kb] = *(const bf16x8*)(ab + kb * 16);

        #pragma unroll 1
        for (int t = 0; t < TO_TILES; t += 2) {
            const unsigned short* a1 = ab + (size_t)(t + 1) * 32 * KDIM_A;
            #pragma unroll
            for (int kb = 0; kb < 5; kb++) An[kb] = *(const bf16x8*)(a1 + kb * 16);
            CHAIN(Ac, Bf0, rmin0)
            CHAIN(Ac, Bf1, rmin1)
            const unsigned short* a2 = ab + (size_t)((t + 2) & (TO_TILES - 1)) * 32 * KDIM_A;
            #pragma unroll
            for (int kb = 0; kb < 5; kb++) Ac[kb] = *(const bf16x8*)(a2 + kb * 16);
            CHAIN(An, Bf0, rmin0)
            CHAIN(An, Bf1, rmin1)
        }

        rmin0 = fminf(rmin0, __shfl_xor(rmin0, 32));
        rmin1 = fminf(rmin1, __shfl_xor(rmin1, 32));
        if (lane < 32) {
            atomicMin(minkeys + fg * 64 + l31,      flipf(rmin0));
            atomicMin(minkeys + fg * 64 + 32 + l31, flipf(rmin1));
        }
    }

    grid_barrier(&bar[1], NBLOCKS);

    // ---------- phase 2: sum a_sq + min over rows ----------
    if (gid < N_PTS) {
        float s = a_sq[gid] + unflipf(minkeys[gid]);
        #pragma unroll
        for (int m = 1; m < 64; m <<= 1) s += __shfl_xor(s, m);
        if ((tid & 63) == 0) atomicAdd(out, s);
    }
}

extern "C" void kernel_launch(void* const* d_in, const int* in_sizes, int n_in,
                              void* d_out, int out_size, void* d_ws, size_t ws_size,
                              hipStream_t stream) {
    const float* from_pts = (const float*)d_in[0];
    const float* to_pts   = (const float*)d_in[1];
    char* ws = (char*)d_ws;
    unsigned*       minkeys = (unsigned*)ws;                          //  64 KB
    float*          a_sq    = (float*)(ws + (64 << 10));              //  64 KB
    unsigned*       bar     = (unsigned*)(ws + (128 << 10));          //  256 B
    unsigned short* Bfrom   = (unsigned short*)(ws + (192 << 10));    //   2 MB
    unsigned short* Ato     = (unsigned short*)(ws + (192 << 10) + (2 << 20)); // 2.56 MB

    hipMemsetAsync(bar, 0, 256, stream);   // barrier counters (graph memset node)
    fused_kernel<<<NBLOCKS, 256, 0, stream>>>(from_pts, to_pts, Bfrom, Ato,
                                              a_sq, minkeys, bar, (float*)d_out);
}

// Round 6
// 117.592 us; speedup vs baseline: 4.4017x; 2.7194x over previous
//
#include <hip/hip_runtime.h>
#include <stdint.h>

// N=M=16384, D=64 fp32. dist[n,m] = a_sq[n] + b_sq[m] - 2 a.b; out = sum_n min_m.
// Orientation: A(streamed) = TO points (K=80: dims 0..63, bsq at k=64),
// B(resident) = -2*FROM (K=64 + constant 1.0 ext fragment). C[row=to][col=from]
// -> per-lane min3-tree over 16 rows => 1 running min per col-subtile (in-lane,
// so no 16-wide running-min register array; VGPR stays ~60, no spills).
// R4/R5 lesson: software grid barriers cost ~125 us each on 8 non-coherent
// XCDs (acquire-invalidate storms / coherent-point RMW). Split launches give
// the same visibility via stream order for ~2 us each.
#define N_PTS 16384
#define KDIM_A 80
#define KDIM_B 64
#define NBLOCKS 1024          // 4 blocks/CU x 256 CUs
#define TSPLITS 16
#define TO_CHUNK (N_PTS / TSPLITS)   // 1024 TO pts per wave
#define TO_TILES (TO_CHUNK / 32)     // 32 tiles of 32 TO pts

typedef __attribute__((ext_vector_type(8)))  short bf16x8;
typedef __attribute__((ext_vector_type(16))) float f32x16;

__device__ __forceinline__ unsigned short f2bf(float f) {
    unsigned u = __float_as_uint(f);
    u += 0x7FFFu + ((u >> 16) & 1u);   // RNE
    return (unsigned short)(u >> 16);
}
__device__ __forceinline__ float tree16(f32x16 a) {
    float m0 = fminf(fminf(a[0],  a[1]),  a[2]);
    float m1 = fminf(fminf(a[3],  a[4]),  a[5]);
    float m2 = fminf(fminf(a[6],  a[7]),  a[8]);
    float m3 = fminf(fminf(a[9],  a[10]), a[11]);
    float m4 = fminf(fminf(a[12], a[13]), a[14]);
    float m5 = fminf(fminf(a[15], m0), m1);
    return fminf(fminf(fminf(m2, m3), m4), m5);
}

// ---------- prep: fp32 -> bf16 operands + norms (coalesced, 8 thr/row) ----
__global__ __launch_bounds__(256) void prep_kernel(
        const float* __restrict__ from_pts, const float* __restrict__ to_pts,
        float* __restrict__ a_sq, unsigned short* __restrict__ Bfrom,
        unsigned short* __restrict__ Ato) {
    int gid = blockIdx.x * 256 + threadIdx.x;   // 0 .. 262143
    int row = gid >> 3;                 // 0..32767 (FROM then TO)
    int sub = gid & 7;                  // 8 threads per row
    bool isFrom = row < N_PTS;
    int r = row & (N_PTS - 1);
    const float* src = isFrom ? from_pts : to_pts;
    float4 v0 = ((const float4*)src)[r * 16 + sub * 2];
    float4 v1 = ((const float4*)src)[r * 16 + sub * 2 + 1];
    float s = v0.x*v0.x + v0.y*v0.y + v0.z*v0.z + v0.w*v0.w
            + v1.x*v1.x + v1.y*v1.y + v1.z*v1.z + v1.w*v1.w;
    s += __shfl_xor(s, 1); s += __shfl_xor(s, 2); s += __shfl_xor(s, 4);
    float sc = isFrom ? -2.0f : 1.0f;
    union { unsigned short u[8]; uint4 q; } w;
    w.u[0] = f2bf(v0.x * sc); w.u[1] = f2bf(v0.y * sc);
    w.u[2] = f2bf(v0.z * sc); w.u[3] = f2bf(v0.w * sc);
    w.u[4] = f2bf(v1.x * sc); w.u[5] = f2bf(v1.y * sc);
    w.u[6] = f2bf(v1.z * sc); w.u[7] = f2bf(v1.w * sc);
    if (isFrom) {
        *(uint4*)(Bfrom + (size_t)r * KDIM_B + sub * 8) = w.q;
        if (sub == 0) a_sq[r] = s;
    } else {
        *(uint4*)(Ato + (size_t)r * KDIM_A + sub * 8) = w.q;
        if (sub == 0) {                 // ext block: bsq at k=64, zeros after
            uint4 z = {0u, 0u, 0u, 0u};
            uint4 e = z;
            e.x = (unsigned)f2bf(s);
            *(uint4*)(Ato + (size_t)r * KDIM_A + 64) = e;
            *(uint4*)(Ato + (size_t)r * KDIM_A + 72) = z;
        }
    }
}

#define CHAIN(X, BF, RM)                                                        \
    {                                                                           \
        f32x16 acc = __builtin_amdgcn_mfma_f32_32x32x16_bf16(X[0], BF[0], zero, 0, 0, 0); \
        acc = __builtin_amdgcn_mfma_f32_32x32x16_bf16(X[1], BF[1], acc, 0, 0, 0); \
        acc = __builtin_amdgcn_mfma_f32_32x32x16_bf16(X[2], BF[2], acc, 0, 0, 0); \
        acc = __builtin_amdgcn_mfma_f32_32x32x16_bf16(X[3], BF[3], acc, 0, 0, 0); \
        acc = __builtin_amdgcn_mfma_f32_32x32x16_bf16(X[4], Bext, acc, 0, 0, 0); \
        RM = fminf(RM, tree16(acc));                                            \
    }

// ---------- main: MFMA + in-lane min; plain stores to pmin[ts][row] -------
__global__ __launch_bounds__(256, 4) void main_kernel(
        const unsigned short* __restrict__ Bfrom,
        const unsigned short* __restrict__ Ato,
        float* __restrict__ pmin) {
    const int tid = threadIdx.x;
    const int lane = tid & 63;
    const int l31 = lane & 31;
    const int h   = lane >> 5;
    const int wid = (blockIdx.x << 2) + (tid >> 6);   // 0..4095
    const int fg  = wid & 255;          // 64 FROM pts per wave
    const int ts  = wid >> 8;           // block's 4 waves: same ts (shared A stream)

    // resident FROM fragments, 2 col-subtiles x 4 k-blocks
    bf16x8 Bf0[4], Bf1[4];
    {
        const unsigned short* br = Bfrom + (size_t)(fg * 64 + l31) * KDIM_B + h * 8;
        #pragma unroll
        for (int kb = 0; kb < 4; kb++) {
            Bf0[kb] = *(const bf16x8*)(br + kb * 16);
            Bf1[kb] = *(const bf16x8*)(br + 32 * KDIM_B + kb * 16);
        }
    }
    // constant B ext fragment: B[n][k=64] = 1.0 (h==0, j==0 slot)
    bf16x8 Bext;
    #pragma unroll
    for (int j = 0; j < 8; j++) Bext[j] = 0;
    if (h == 0) Bext[0] = (short)0x3F80;

    f32x16 zero;
    #pragma unroll
    for (int r = 0; r < 16; r++) zero[r] = 0.0f;

    float rmin0 = 3.0e38f, rmin1 = 3.0e38f;
    const unsigned short* ab = Ato + (size_t)(ts * TO_CHUNK + l31) * KDIM_A + h * 8;

    bf16x8 Ac[5], An[5];
    #pragma unroll
    for (int kb = 0; kb < 5; kb++) Ac[kb] = *(const bf16x8*)(ab + kb * 16);

    #pragma unroll 1
    for (int t = 0; t < TO_TILES; t += 2) {
        const unsigned short* a1 = ab + (size_t)(t + 1) * 32 * KDIM_A;
        #pragma unroll
        for (int kb = 0; kb < 5; kb++) An[kb] = *(const bf16x8*)(a1 + kb * 16);
        CHAIN(Ac, Bf0, rmin0)
        CHAIN(Ac, Bf1, rmin1)
        const unsigned short* a2 = ab + (size_t)((t + 2) & (TO_TILES - 1)) * 32 * KDIM_A;
        #pragma unroll
        for (int kb = 0; kb < 5; kb++) Ac[kb] = *(const bf16x8*)(a2 + kb * 16);
        CHAIN(An, Bf0, rmin0)
        CHAIN(An, Bf1, rmin1)
    }

    // cross-half min, then plain store: (ts,fg) is wave-unique -> no atomics
    rmin0 = fminf(rmin0, __shfl_xor(rmin0, 32));
    rmin1 = fminf(rmin1, __shfl_xor(rmin1, 32));
    if (lane < 32) {
        pmin[(size_t)ts * N_PTS + fg * 64 + l31]      = rmin0;
        pmin[(size_t)ts * N_PTS + fg * 64 + 32 + l31] = rmin1;
    }
}

// ---------- finish: min over 16 splits, add a_sq, global sum --------------
__global__ __launch_bounds__(256) void finish_kernel(
        const float* __restrict__ a_sq, const float* __restrict__ pmin,
        float* __restrict__ out) {
    int r = blockIdx.x * 256 + threadIdx.x;
    float m = pmin[r];
    #pragma unroll
    for (int s = 1; s < TSPLITS; s++)
        m = fminf(m, pmin[(size_t)s * N_PTS + r]);
    float v = a_sq[r] + m;
    #pragma unroll
    for (int k = 1; k < 64; k <<= 1) v += __shfl_xor(v, k);
    __shared__ float red[4];
    if ((threadIdx.x & 63) == 0) red[threadIdx.x >> 6] = v;
    __syncthreads();
    if (threadIdx.x == 0)
        atomicAdd(out, red[0] + red[1] + red[2] + red[3]);
}

extern "C" void kernel_launch(void* const* d_in, const int* in_sizes, int n_in,
                              void* d_out, int out_size, void* d_ws, size_t ws_size,
                              hipStream_t stream) {
    const float* from_pts = (const float*)d_in[0];
    const float* to_pts   = (const float*)d_in[1];
    char* ws = (char*)d_ws;
    float*          a_sq  = (float*)ws;                                //   64 KB
    float*          pmin  = (float*)(ws + (64 << 10));                 //    1 MB
    unsigned short* Bfrom = (unsigned short*)(ws + (64 << 10) + (1 << 20));           // 2 MB
    unsigned short* Ato   = (unsigned short*)(ws + (64 << 10) + (1 << 20) + (2 << 20)); // 2.56 MB

    hipMemsetAsync(d_out, 0, sizeof(float), stream);   // harness poisons d_out
    prep_kernel<<<(2 * N_PTS * 8) / 256, 256, 0, stream>>>(from_pts, to_pts,
                                                           a_sq, Bfrom, Ato);
    main_kernel<<<NBLOCKS, 256, 0, stream>>>(Bfrom, Ato, pmin);
    finish_kernel<<<N_PTS / 256, 256, 0, stream>>>(a_sq, pmin, (float*)d_out);
}

// Round 7
// 107.091 us; speedup vs baseline: 4.8333x; 1.0981x over previous
//
#include <hip/hip_runtime.h>
#include <stdint.h>

// N=M=16384, D=64 fp32. dist[n,m] = a_sq[n] + b_sq[m] - 2 a.b; out = sum_n min_m.
// Orientation: A(streamed) = TO points (K=80: dims 0..63, bsq at k=64),
// B(resident) = -2*FROM (K=64 + constant-1.0 ext fragment). C[row=to][col=from]
// -> per-lane min3-tree over 16 rows => 1 running min per col-subtile.
// R6 lesson: double-buffered A (Ac+An) pushed regs to ~130 > 128 cap ->
// 10 MB/launch scratch spill in the K-loop (WRITE_SIZE 11 MB, MfmaUtil 26%).
// Single-buffer A; 4 waves/SIMD hide the L2 latency instead.
#define N_PTS 16384
#define KDIM_A 80
#define KDIM_B 64
#define TSPLITS 32
#define NBLOCKS (256 * TSPLITS / 4)  // 2048: 256 fg-groups x 32 splits / 4 waves
#define TO_CHUNK (N_PTS / TSPLITS)   // 512 TO pts per wave
#define TO_TILES (TO_CHUNK / 32)     // 16 tiles of 32 TO pts

typedef __attribute__((ext_vector_type(8)))  short bf16x8;
typedef __attribute__((ext_vector_type(16))) float f32x16;

__device__ __forceinline__ unsigned short f2bf(float f) {
    unsigned u = __float_as_uint(f);
    u += 0x7FFFu + ((u >> 16) & 1u);   // RNE
    return (unsigned short)(u >> 16);
}
__device__ __forceinline__ float tree16(f32x16 a) {
    float m0 = fminf(fminf(a[0],  a[1]),  a[2]);
    float m1 = fminf(fminf(a[3],  a[4]),  a[5]);
    float m2 = fminf(fminf(a[6],  a[7]),  a[8]);
    float m3 = fminf(fminf(a[9],  a[10]), a[11]);
    float m4 = fminf(fminf(a[12], a[13]), a[14]);
    float m5 = fminf(fminf(a[15], m0), m1);
    return fminf(fminf(fminf(m2, m3), m4), m5);
}

// ---------- prep: fp32 -> bf16 operands + norms (coalesced, 8 thr/row) ----
__global__ __launch_bounds__(256) void prep_kernel(
        const float* __restrict__ from_pts, const float* __restrict__ to_pts,
        float* __restrict__ a_sq, unsigned short* __restrict__ Bfrom,
        unsigned short* __restrict__ Ato) {
    int gid = blockIdx.x * 256 + threadIdx.x;   // 0 .. 262143
    int row = gid >> 3;                 // 0..32767 (FROM then TO)
    int sub = gid & 7;                  // 8 threads per row
    bool isFrom = row < N_PTS;
    int r = row & (N_PTS - 1);
    const float* src = isFrom ? from_pts : to_pts;
    float4 v0 = ((const float4*)src)[r * 16 + sub * 2];
    float4 v1 = ((const float4*)src)[r * 16 + sub * 2 + 1];
    float s = v0.x*v0.x + v0.y*v0.y + v0.z*v0.z + v0.w*v0.w
            + v1.x*v1.x + v1.y*v1.y + v1.z*v1.z + v1.w*v1.w;
    s += __shfl_xor(s, 1); s += __shfl_xor(s, 2); s += __shfl_xor(s, 4);
    float sc = isFrom ? -2.0f : 1.0f;
    union { unsigned short u[8]; uint4 q; } w;
    w.u[0] = f2bf(v0.x * sc); w.u[1] = f2bf(v0.y * sc);
    w.u[2] = f2bf(v0.z * sc); w.u[3] = f2bf(v0.w * sc);
    w.u[4] = f2bf(v1.x * sc); w.u[5] = f2bf(v1.y * sc);
    w.u[6] = f2bf(v1.z * sc); w.u[7] = f2bf(v1.w * sc);
    if (isFrom) {
        *(uint4*)(Bfrom + (size_t)r * KDIM_B + sub * 8) = w.q;
        if (sub == 0) a_sq[r] = s;
    } else {
        *(uint4*)(Ato + (size_t)r * KDIM_A + sub * 8) = w.q;
        if (sub == 0) {                 // ext block: bsq at k=64, zeros after
            uint4 z = {0u, 0u, 0u, 0u};
            uint4 e = z;
            e.x = (unsigned)f2bf(s);
            *(uint4*)(Ato + (size_t)r * KDIM_A + 64) = e;
            *(uint4*)(Ato + (size_t)r * KDIM_A + 72) = z;
        }
    }
}

#define CHAIN(X, BF, RM)                                                        \
    {                                                                           \
        f32x16 acc = __builtin_amdgcn_mfma_f32_32x32x16_bf16(X[0], BF[0], zero, 0, 0, 0); \
        acc = __builtin_amdgcn_mfma_f32_32x32x16_bf16(X[1], BF[1], acc, 0, 0, 0); \
        acc = __builtin_amdgcn_mfma_f32_32x32x16_bf16(X[2], BF[2], acc, 0, 0, 0); \
        acc = __builtin_amdgcn_mfma_f32_32x32x16_bf16(X[3], BF[3], acc, 0, 0, 0); \
        acc = __builtin_amdgcn_mfma_f32_32x32x16_bf16(X[4], Bext, acc, 0, 0, 0); \
        RM = fminf(RM, tree16(acc));                                            \
    }

// ---------- main: MFMA + in-lane min; plain stores to pmin[ts][row] -------
// ~104 regs (Bf 32, Ac 20, acc 16, zero 16, Bext 4, rest addr/temps):
// fits the 128-reg cap of (256,4) with NO spills. Block's 4 waves share the
// same ts => A-stream loads mostly served by L1.
__global__ __launch_bounds__(256, 4) void main_kernel(
        const unsigned short* __restrict__ Bfrom,
        const unsigned short* __restrict__ Ato,
        float* __restrict__ pmin) {
    const int tid = threadIdx.x;
    const int lane = tid & 63;
    const int l31 = lane & 31;
    const int h   = lane >> 5;
    const int wid = (blockIdx.x << 2) + (tid >> 6);   // 0..8191
    const int fg  = wid & 255;          // 64 FROM pts per wave
    const int ts  = wid >> 8;           // block's 4 waves: same ts

    // resident FROM fragments, 2 col-subtiles x 4 k-blocks
    bf16x8 Bf0[4], Bf1[4];
    {
        const unsigned short* br = Bfrom + (size_t)(fg * 64 + l31) * KDIM_B + h * 8;
        #pragma unroll
        for (int kb = 0; kb < 4; kb++) {
            Bf0[kb] = *(const bf16x8*)(br + kb * 16);
            Bf1[kb] = *(const bf16x8*)(br + 32 * KDIM_B + kb * 16);
        }
    }
    // constant B ext fragment: B[n][k=64] = 1.0 (h==0, j==0 slot)
    bf16x8 Bext;
    #pragma unroll
    for (int j = 0; j < 8; j++) Bext[j] = 0;
    if (h == 0) Bext[0] = (short)0x3F80;

    f32x16 zero;
    #pragma unroll
    for (int r = 0; r < 16; r++) zero[r] = 0.0f;

    float rmin0 = 3.0e38f, rmin1 = 3.0e38f;
    const unsigned short* ab = Ato + (size_t)(ts * TO_CHUNK + l31) * KDIM_A + h * 8;

    #pragma unroll 1
    for (int t = 0; t < TO_TILES; t++) {
        const unsigned short* at = ab + (size_t)t * 32 * KDIM_A;
        bf16x8 Ac[5];
        #pragma unroll
        for (int kb = 0; kb < 5; kb++) Ac[kb] = *(const bf16x8*)(at + kb * 16);
        CHAIN(Ac, Bf0, rmin0)
        CHAIN(Ac, Bf1, rmin1)
    }

    // cross-half min, then plain store: (ts,fg) is wave-unique -> no atomics
    rmin0 = fminf(rmin0, __shfl_xor(rmin0, 32));
    rmin1 = fminf(rmin1, __shfl_xor(rmin1, 32));
    if (lane < 32) {
        pmin[(size_t)ts * N_PTS + fg * 64 + l31]      = rmin0;
        pmin[(size_t)ts * N_PTS + fg * 64 + 32 + l31] = rmin1;
    }
}

// ---------- finish: min over 32 splits, add a_sq, global sum --------------
__global__ __launch_bounds__(256) void finish_kernel(
        const float* __restrict__ a_sq, const float* __restrict__ pmin,
        float* __restrict__ out) {
    int r = blockIdx.x * 256 + threadIdx.x;
    float m = pmin[r];
    #pragma unroll
    for (int s = 1; s < TSPLITS; s++)
        m = fminf(m, pmin[(size_t)s * N_PTS + r]);
    float v = a_sq[r] + m;
    #pragma unroll
    for (int k = 1; k < 64; k <<= 1) v += __shfl_xor(v, k);
    __shared__ float red[4];
    if ((threadIdx.x & 63) == 0) red[threadIdx.x >> 6] = v;
    __syncthreads();
    if (threadIdx.x == 0)
        atomicAdd(out, red[0] + red[1] + red[2] + red[3]);
}

extern "C" void kernel_launch(void* const* d_in, const int* in_sizes, int n_in,
                              void* d_out, int out_size, void* d_ws, size_t ws_size,
                              hipStream_t stream) {
    const float* from_pts = (const float*)d_in[0];
    const float* to_pts   = (const float*)d_in[1];
    char* ws = (char*)d_ws;
    float*          a_sq  = (float*)ws;                                //   64 KB
    float*          pmin  = (float*)(ws + (64 << 10));                 //    2 MB
    unsigned short* Bfrom = (unsigned short*)(ws + (64 << 10) + (2 << 20));           // 2 MB
    unsigned short* Ato   = (unsigned short*)(ws + (64 << 10) + (2 << 20) + (2 << 20)); // 2.56 MB

    hipMemsetAsync(d_out, 0, sizeof(float), stream);   // harness poisons d_out
    prep_kernel<<<(2 * N_PTS * 8) / 256, 256, 0, stream>>>(from_pts, to_pts,
                                                           a_sq, Bfrom, Ato);
    main_kernel<<<NBLOCKS, 256, 0, stream>>>(Bfrom, Ato, pmin);
    finish_kernel<<<N_PTS / 256, 256, 0, stream>>>(a_sq, pmin, (float*)d_out);
}